// Round 10
// baseline (181.030 us; speedup 1.0000x reference)
//
#include <hip/hip_runtime.h>
#include <hip/hip_bf16.h>

#define NN 16384
#define NE 65536
#define NB 512          // persistent conv grid (16 leaves x 32)

typedef __attribute__((ext_vector_type(8))) short short8;
typedef __attribute__((ext_vector_type(4))) float f32x4;

using bf16 = __hip_bfloat16;

__device__ __forceinline__ float b2f(bf16 v){ return __bfloat162float(v); }
__device__ __forceinline__ bf16 f2b(float v){ return __float2bfloat16(v); }
__device__ __forceinline__ unsigned bfbits(float v){
    bf16 h = f2b(v);
    return (unsigned)*(unsigned short*)&h;
}

// ---- coherent (cross-XCD) coalesced ops: plain VMEM with sc0 sc1 ----
__device__ __forceinline__ void cohSt(unsigned* p, unsigned v){
    asm volatile("global_store_dword %0, %1, off sc0 sc1"
                 :: "v"((unsigned long long)(uintptr_t)p), "v"(v) : "memory");
}
__device__ __forceinline__ unsigned cohLd1(const unsigned* p){
    unsigned v;
    asm volatile("global_load_dword %0, %1, off sc0 sc1\n\ts_waitcnt vmcnt(0)"
                 : "=&v"(v) : "v"((unsigned long long)(uintptr_t)p) : "memory");
    return v;
}

struct MA {
    const float *x, *y, *rel, *a;
    const int *send, *recv;
    const float *W[4], *P[4];
    const float *bb[4], *bs[4], *bo[4], *bm[4], *bv[4];
    float* g;                    // [4][NE][16]
    unsigned *curs, *csr, *bar;  // bar: root@0, leaf k @ 64*(1+k), gen @ 64*17
    unsigned *h1u, *xou, *h3u;   // coherent intermediates, 2 bf16 / uint
    bf16 *Bp, *xyc;
    float* outp;
};

// ---------------- fenceless grid barrier: 2-level relaxed counters ----------
__device__ __forceinline__ void lightbar(unsigned* bar){
    __syncthreads();   // drains each wave's vmcnt -> coherent stores complete
    if(threadIdx.x == 0){
        unsigned* gen  = bar + 64*17;
        unsigned g0 = __hip_atomic_load(gen, __ATOMIC_RELAXED, __HIP_MEMORY_SCOPE_AGENT);
        unsigned* leaf = bar + 64*(1 + (blockIdx.x & 15));
        unsigned a = __hip_atomic_fetch_add(leaf, 1u, __ATOMIC_RELAXED, __HIP_MEMORY_SCOPE_AGENT);
        bool done = false;
        if(a == (NB/16 - 1u)){
            __hip_atomic_store(leaf, 0u, __ATOMIC_RELAXED, __HIP_MEMORY_SCOPE_AGENT);
            unsigned rr = __hip_atomic_fetch_add(bar, 1u, __ATOMIC_RELAXED, __HIP_MEMORY_SCOPE_AGENT);
            if(rr == 15u){
                __hip_atomic_store(bar, 0u, __ATOMIC_RELAXED, __HIP_MEMORY_SCOPE_AGENT);
                __hip_atomic_fetch_add(gen, 1u, __ATOMIC_RELAXED, __HIP_MEMORY_SCOPE_AGENT);
                done = true;
            }
        }
        if(!done){
            while(__hip_atomic_load(gen, __ATOMIC_RELAXED, __HIP_MEMORY_SCOPE_AGENT) == g0)
                __builtin_amdgcn_s_sleep(32);
        }
    }
    __syncthreads();
}

// ================= k_setup: countfill + g | W pack | xyc =================
__global__ __launch_bounds__(256) void k_setup(MA A){
    int b = blockIdx.x;
    if(b < 256){
        int e = b*256 + threadIdx.x;
        int rv = A.recv[e];
        unsigned pos = atomicAdd(&A.curs[rv], 1u);
        if(pos < 32u) A.csr[(unsigned)rv*32u + pos] = ((unsigned)e << 14) | (unsigned)A.send[e];
        float r0 = A.rel[e*3+0], r1 = A.rel[e*3+1], r2 = A.rel[e*3+2];
        float av = A.a[e];
        for(int c=0;c<4;c++){
            const float* P = A.P[c];
            float lg[16]; float mx = -1e30f;
            #pragma unroll
            for(int k=0;k<16;k++){
                float v = r0*P[k] + r1*P[16+k] + r2*P[32+k];
                lg[k] = v; mx = fmaxf(mx, v);
            }
            float ssum = 0.f;
            #pragma unroll
            for(int k=0;k<16;k++){ lg[k] = __expf(lg[k]-mx); ssum += lg[k]; }
            float inv = av/ssum;
            float* go = A.g + ((size_t)c*NE + e)*16;
            #pragma unroll
            for(int j=0;j<4;j++){
                ((float4*)go)[j] = make_float4(lg[j*4]*inv, lg[j*4+1]*inv,
                                               lg[j*4+2]*inv, lg[j*4+3]*inv);
            }
        }
        return;
    }
    if(b < 336){
        int t = (b-256)*256 + threadIdx.x;
        const float* W; int Cout; int base; int tl;
        if(t < 8192)      { W=A.W[0]; Cout=64; base=0;     tl=t; }
        else if(t < 12288){ W=A.W[1]; Cout=32; base=8192;  tl=t-8192; }
        else if(t < 16384){ W=A.W[2]; Cout=64; base=12288; tl=t-12288; }
        else              { W=A.W[3]; Cout=32; base=16384; tl=t-16384; }
        int l  = tl & 63;
        int NCT = Cout >> 4;
        int ct = (tl >> 6) % NCT;
        int ks = (tl >> 6) / NCT;
        int col = ct*16 + (l & 15);
        int k0  = ks*32 + ((l >> 4) & 3)*8;
        short8 v;
        #pragma unroll
        for(int j=0;j<8;j++){
            bf16 h = f2b(W[(size_t)(k0+j)*Cout + col]);
            v[j] = (short)*(unsigned short*)&h;
        }
        ((short8*)A.Bp)[base + tl] = v;
        return;
    }
    // xyc[n][64] bf16 = [x[n] | y[n]]
    int t = (b-336)*256 + threadIdx.x;   // [0, 32768)
    int n = t >> 1, half = t & 1;
    const float* src = half ? (A.y + n*32) : (A.x + n*32);
    bf16* dst = A.xyc + (size_t)n*64 + half*32;
    #pragma unroll
    for(int j=0;j<4;j++){
        float4 v0 = ((const float4*)src)[2*j];
        float4 v1 = ((const float4*)src)[2*j+1];
        short8 o; bf16 h;
        h = f2b(v0.x); o[0]=(short)*(unsigned short*)&h;
        h = f2b(v0.y); o[1]=(short)*(unsigned short*)&h;
        h = f2b(v0.z); o[2]=(short)*(unsigned short*)&h;
        h = f2b(v0.w); o[3]=(short)*(unsigned short*)&h;
        h = f2b(v1.x); o[4]=(short)*(unsigned short*)&h;
        h = f2b(v1.y); o[5]=(short)*(unsigned short*)&h;
        h = f2b(v1.z); o[6]=(short)*(unsigned short*)&h;
        h = f2b(v1.w); o[7]=(short)*(unsigned short*)&h;
        ((short8*)dst)[j] = o;
    }
}

// ================= conv phase (persistent): agg -> LDS -> MFMA -> epilogue ==
template<int CIN, int NCT, int MODE, bool COHIN, bool F32OUT>
__device__ __forceinline__ void convp(
    char* sT, const void* fin,
    const float* g, const unsigned* csr, const unsigned* curs,
    const bf16* Bp, const float* bias,
    const float* bns, const float* bno,
    const float* bnm, const float* bnv,
    const float* x, const float* y, void* outv)
{
    constexpr int KD   = CIN*16;
    constexpr int ROWB = KD*2;
    int wv = threadIdx.x >> 6, lane = threadIdx.x & 63;
    const int i     = (CIN==64) ? lane : (lane & 31);
    const int kbase = (CIN==64) ? 0 : ((lane >> 5) * 8);
    constexpr int KPL = (CIN==64) ? 16 : 8;

    for(int tile=0; tile<2; tile++){
        int nbase = (tile*NB + blockIdx.x)*16;
        int node  = nbase + wv;

        // ---------- aggregation (one node per wave) ----------
        const unsigned* crow = csr + (unsigned)node*32u;
        unsigned cnt = curs[node]; if(cnt > 32u) cnt = 32u;
        uint4 c0 = ((const uint4*)crow)[0];
        uint4 c1 = ((const uint4*)crow)[1];
        unsigned uu[8] = {c0.x,c0.y,c0.z,c0.w, c1.x,c1.y,c1.z,c1.w};

        float acc[KPL];
        #pragma unroll
        for(int r=0;r<KPL;r++) acc[r] = 0.f;

        auto edgeAcc = [&](int eid, float fe){
            const float4* gp = (const float4*)&g[(size_t)eid*16 + kbase];
            if(CIN==64){
                float4 g0=gp[0], g1=gp[1], g2=gp[2], g3=gp[3];
                acc[0]  += g0.x*fe; acc[1]  += g0.y*fe; acc[2]  += g0.z*fe; acc[3]  += g0.w*fe;
                acc[4]  += g1.x*fe; acc[5]  += g1.y*fe; acc[6]  += g1.z*fe; acc[7]  += g1.w*fe;
                acc[8]  += g2.x*fe; acc[9]  += g2.y*fe; acc[10] += g2.z*fe; acc[11] += g2.w*fe;
                acc[12] += g3.x*fe; acc[13] += g3.y*fe; acc[14] += g3.z*fe; acc[15] += g3.w*fe;
            } else {
                float4 g0=gp[0], g1=gp[1];
                acc[0] += g0.x*fe; acc[1] += g0.y*fe; acc[2] += g0.z*fe; acc[3] += g0.w*fe;
                acc[4] += g1.x*fe; acc[5] += g1.y*fe; acc[6] += g1.z*fe; acc[7] += g1.w*fe;
            }
        };

        if(COHIN){
            const unsigned* hu = (const unsigned*)fin;
            const unsigned widx = (CIN==64) ? ((unsigned)lane >> 1)
                                            : (((unsigned)lane & 31u) >> 1);
            #define CADDR(J) ((unsigned long long)(uintptr_t)(hu + (size_t)(uu[J] & 16383u)*(CIN/2) + widx))
            unsigned f0,f1,f2,f3,f4,f5,f6,f7;
            {
                unsigned long long A0=CADDR(0),A1=CADDR(1),A2=CADDR(2),A3=CADDR(3),
                                   A4=CADDR(4),A5=CADDR(5),A6=CADDR(6),A7=CADDR(7);
                asm volatile(
                    "global_load_dword %0, %8, off sc0 sc1\n\t"
                    "global_load_dword %1, %9, off sc0 sc1\n\t"
                    "global_load_dword %2, %10, off sc0 sc1\n\t"
                    "global_load_dword %3, %11, off sc0 sc1\n\t"
                    "global_load_dword %4, %12, off sc0 sc1\n\t"
                    "global_load_dword %5, %13, off sc0 sc1\n\t"
                    "global_load_dword %6, %14, off sc0 sc1\n\t"
                    "global_load_dword %7, %15, off sc0 sc1\n\t"
                    "s_waitcnt vmcnt(0)"
                    : "=&v"(f0),"=&v"(f1),"=&v"(f2),"=&v"(f3),
                      "=&v"(f4),"=&v"(f5),"=&v"(f6),"=&v"(f7)
                    : "v"(A0),"v"(A1),"v"(A2),"v"(A3),
                      "v"(A4),"v"(A5),"v"(A6),"v"(A7)
                    : "memory");
            }
            __builtin_amdgcn_sched_barrier(0);
            #undef CADDR
            unsigned fw[8] = {f0,f1,f2,f3,f4,f5,f6,f7};
            #pragma unroll
            for(int j=0;j<8;j++){
                if((unsigned)j < cnt){
                    unsigned w16 = (i & 1) ? (fw[j] >> 16) : (fw[j] & 0xffffu);
                    edgeAcc((int)(uu[j] >> 14), __uint_as_float(w16 << 16));
                }
            }
            for(unsigned j=8; j<cnt; j++){
                unsigned u = crow[j];
                unsigned wv_ = cohLd1(hu + (size_t)(u & 16383u)*(CIN/2) + widx);
                unsigned w16 = (i & 1) ? (wv_ >> 16) : (wv_ & 0xffffu);
                edgeAcc((int)(u >> 14), __uint_as_float(w16 << 16));
            }
        } else {
            const bf16* fAb = (const bf16*)fin;
            #pragma unroll
            for(int j=0;j<8;j++){
                if((unsigned)j < cnt){
                    unsigned u = uu[j];
                    edgeAcc((int)(u >> 14), b2f(fAb[(u & 16383u)*CIN + i]));
                }
            }
            for(unsigned j=8; j<cnt; j++){
                unsigned u = crow[j];
                edgeAcc((int)(u >> 14), b2f(fAb[(u & 16383u)*CIN + i]));
            }
        }

        // ---------- LDS write (swizzled) ----------
        unsigned xo_ = (unsigned)((wv & 7) << 4);
        if(CIN==64){
            #pragma unroll
            for(int k=0;k<16;k++){
                unsigned byte = (unsigned)wv*ROWB + ((((unsigned)(k*64 + lane))*2u) ^ xo_);
                *(bf16*)(sT + byte) = f2b(acc[k]);
            }
        } else {
            #pragma unroll
            for(int r=0;r<8;r++){
                unsigned byte = (unsigned)wv*ROWB + ((((unsigned)((kbase+r)*32 + i))*2u) ^ xo_);
                *(bf16*)(sT + byte) = f2b(acc[r]);
            }
        }
        __syncthreads();

        // ---------- GEMM + epilogue (waves 0..NCT-1) ----------
        if(wv < NCT){
            int r = lane & 15, h = lane >> 4;
            int c = wv;
            const short8* Bp8 = (const short8*)Bp;
            f32x4 acc4 = (f32x4){0.f,0.f,0.f,0.f};
            unsigned xr = (unsigned)((r & 7) << 4);
            #pragma unroll 8
            for(int ks=0; ks<KD/32; ks++){
                unsigned ab = (unsigned)r*ROWB + (((unsigned)(ks*64 + h*16)) ^ xr);
                short8 af  = *(const short8*)(sT + ab);
                short8 bfr = Bp8[(ks*NCT + c)*64 + lane];
                acc4 = __builtin_amdgcn_mfma_f32_16x16x32_bf16(af, bfr, acc4, 0, 0, 0);
            }
            const int Cout = NCT*16;
            int col = c*16 + r;
            float inv = rsqrtf(bnv[col] + 1e-5f);
            float al  = bns[col] * inv;
            float be  = al*(bias[col] - bnm[col]) + bno[col];
            #pragma unroll
            for(int j=0;j<4;j++){
                int rr = nbase + h*4 + j;
                float v = al*acc4[j] + be;
                float res;
                if(MODE==0){
                    res = fmaxf(v, 0.f);
                } else {
                    float wei = 1.f/(1.f + __expf(-v));
                    res = 2.f*x[rr*32 + col]*wei + 2.f*y[rr*32 + col]*(1.f - wei);
                }
                if(F32OUT){
                    ((float*)outv)[(size_t)rr*32 + col] = res;
                } else {
                    unsigned mine  = bfbits(res);
                    unsigned other = (unsigned)__shfl_xor((int)mine, 1, 64);
                    if((lane & 1) == 0){
                        cohSt((unsigned*)outv + (size_t)rr*(Cout/2) + (col>>1),
                              mine | (other << 16));
                    }
                }
            }
        }
        __syncthreads();
    }
}

// ---------------- persistent 4-conv kernel (3 fenceless barriers) ----------
__global__ __launch_bounds__(1024, 8) void k_conv4x(MA A){
    __shared__ __align__(16) char sT[32768];
    convp<64,4,0,false,false>(sT, A.xyc, A.g,                  A.csr, A.curs,
        A.Bp,                  A.bb[0],A.bs[0],A.bo[0],A.bm[0],A.bv[0], nullptr,nullptr, A.h1u);
    lightbar(A.bar);
    convp<64,2,1,true ,false>(sT, A.h1u, A.g + (size_t)1*NE*16, A.csr, A.curs,
        A.Bp + (size_t)8192*8, A.bb[1],A.bs[1],A.bo[1],A.bm[1],A.bv[1], A.x,A.y, A.xou);
    lightbar(A.bar);
    convp<32,4,0,true ,false>(sT, A.xou, A.g + (size_t)2*NE*16, A.csr, A.curs,
        A.Bp + (size_t)12288*8,A.bb[2],A.bs[2],A.bo[2],A.bm[2],A.bv[2], nullptr,nullptr, A.h3u);
    lightbar(A.bar);
    convp<64,2,1,true ,true >(sT, A.h3u, A.g + (size_t)3*NE*16, A.csr, A.curs,
        A.Bp + (size_t)16384*8,A.bb[3],A.bs[3],A.bo[3],A.bm[3],A.bv[3], A.x,A.y, A.outp);
}

// ---------------- launch ----------------
extern "C" void kernel_launch(void* const* d_in, const int* in_sizes, int n_in,
                              void* d_out, int out_size, void* d_ws, size_t ws_size,
                              hipStream_t stream){
    MA A;
    A.x    = (const float*)d_in[0];
    A.y    = (const float*)d_in[1];
    A.send = (const int*)d_in[2];
    A.recv = (const int*)d_in[3];
    A.rel  = (const float*)d_in[4];
    A.a    = (const float*)d_in[5];
    for(int i=0;i<4;i++){
        int base = 6 + i*7;
        A.W[i]  = (const float*)d_in[base+0];
        A.P[i]  = (const float*)d_in[base+1];
        A.bb[i] = (const float*)d_in[base+2];
        A.bs[i] = (const float*)d_in[base+3];
        A.bo[i] = (const float*)d_in[base+4];
        A.bm[i] = (const float*)d_in[base+5];
        A.bv[i] = (const float*)d_in[base+6];
    }
    char* w = (char*)d_ws;
    A.g    = (float*)(w);                      // 16,777,216
    A.curs = (unsigned*)(w + 16777216);        //     65,536
    A.bar  = (unsigned*)(w + 16842752);        //      8,192
    A.csr  = (unsigned*)(w + 16850944);        //  2,097,152
    A.h1u  = (unsigned*)(w + 18948096);        //  2,097,152
    A.xou  = (unsigned*)(w + 21045248);        //  1,048,576
    A.h3u  = (unsigned*)(w + 22093824);        //  2,097,152
    A.Bp   = (bf16*)(w + 24190976);            //    327,680
    A.xyc  = (bf16*)(w + 24518656);            //  2,097,152
    A.outp = (float*)d_out;

    // zero curs + barrier state
    hipMemsetAsync(w + 16777216, 0, 65536 + 8192, stream);
    k_setup <<<464, 256, 0, stream>>>(A);
    k_conv4x<<<NB, 1024, 0, stream>>>(A);
}

// Round 11
// 172.485 us; speedup vs baseline: 1.0495x; 1.0495x over previous
//
#include <hip/hip_runtime.h>
#include <hip/hip_bf16.h>

#define NN 16384
#define NE 65536

typedef __attribute__((ext_vector_type(8))) short short8;
typedef __attribute__((ext_vector_type(4))) float f32x4;

using bf16 = __hip_bfloat16;

__device__ __forceinline__ float b2f(bf16 v){ return __bfloat162float(v); }
__device__ __forceinline__ bf16 f2b(float v){ return __float2bfloat16(v); }

// ================= k_init: zero curs | tap weights g | pack W =================
// blocks [0,64): zero curs ; [64,320): g (e-indexed) ; [320,400): W pack
__global__ __launch_bounds__(256) void k_init(
    unsigned* __restrict__ curs,
    const float* __restrict__ rel, const float* __restrict__ a,
    const float* __restrict__ P1, const float* __restrict__ P2,
    const float* __restrict__ P3, const float* __restrict__ P4,
    float* __restrict__ g,
    const float* __restrict__ W1, const float* __restrict__ W2,
    const float* __restrict__ W3, const float* __restrict__ W4,
    bf16* __restrict__ Bp)
{
    int b = blockIdx.x;
    if(b < 64){
        curs[b*256 + threadIdx.x] = 0u;
        return;
    }
    if(b < 320){
        int e = (b-64)*256 + threadIdx.x;
        float r0 = rel[e*3+0], r1 = rel[e*3+1], r2 = rel[e*3+2];
        float av = a[e];
        const float* Ps[4] = {P1,P2,P3,P4};
        for(int c=0;c<4;c++){
            const float* P = Ps[c];
            float lg[16]; float mx = -1e30f;
            #pragma unroll
            for(int k=0;k<16;k++){
                float v = r0*P[k] + r1*P[16+k] + r2*P[32+k];
                lg[k] = v; mx = fmaxf(mx, v);
            }
            float ssum = 0.f;
            #pragma unroll
            for(int k=0;k<16;k++){ lg[k] = __expf(lg[k]-mx); ssum += lg[k]; }
            float inv = av/ssum;
            float* go = &g[((size_t)c*NE + e)*16];
            #pragma unroll
            for(int j=0;j<4;j++){
                ((float4*)go)[j] = make_float4(lg[j*4]*inv, lg[j*4+1]*inv,
                                               lg[j*4+2]*inv, lg[j*4+3]*inv);
            }
        }
        return;
    }
    // ---- W pack into MFMA B-fragment order ----
    int t = (b-320)*256 + threadIdx.x;
    const float* W; int Cout; int base; int tl;
    if(t < 8192)      { W=W1; Cout=64; base=0;     tl=t; }
    else if(t < 12288){ W=W2; Cout=32; base=8192;  tl=t-8192; }
    else if(t < 16384){ W=W3; Cout=64; base=12288; tl=t-12288; }
    else              { W=W4; Cout=32; base=16384; tl=t-16384; }
    int l  = tl & 63;
    int NCT = Cout >> 4;
    int ct = (tl >> 6) % NCT;
    int ks = (tl >> 6) / NCT;
    int col = ct*16 + (l & 15);
    int k0  = ks*32 + ((l >> 4) & 3)*8;
    short8 v;
    #pragma unroll
    for(int j=0;j<8;j++){
        bf16 h = f2b(W[(size_t)(k0+j)*Cout + col]);
        v[j] = (short)*(unsigned short*)&h;
    }
    ((short8*)Bp)[base + tl] = v;
}

// ================= k_countfill: fixed-capacity buckets, value=(eid<<14|sid) ===
__global__ __launch_bounds__(256) void k_countfill(const int* __restrict__ recv,
                                                   const int* __restrict__ send,
                                                   unsigned* __restrict__ curs,
                                                   unsigned* __restrict__ csr){
    int e = blockIdx.x*256 + threadIdx.x;
    if(e >= NE) return;
    int rv = recv[e];
    unsigned pos = atomicAdd(&curs[rv], 1u);
    if(pos < 32u) csr[(unsigned)rv*32u + pos] = ((unsigned)e << 14) | (unsigned)send[e];
}

// ================= fused conv: wave-per-node agg -> LDS -> MFMA -> epilogue ===
template<int CIN, int NCT, int MODE, bool CONCAT, typename OT>
__global__ __launch_bounds__(1024, 4) void k_conv(
    const void* __restrict__ fAv, const float* __restrict__ fBv,
    const float* __restrict__ g,
    const unsigned* __restrict__ csr, const unsigned* __restrict__ curs,
    const bf16* __restrict__ Bp, const float* __restrict__ bias,
    const float* __restrict__ bns, const float* __restrict__ bno,
    const float* __restrict__ bnm, const float* __restrict__ bnv,
    const float* __restrict__ x, const float* __restrict__ y,
    OT* __restrict__ out)
{
    constexpr int KD   = CIN*16;
    constexpr int ROWB = KD*2;
    __shared__ __align__(16) char sT[16*ROWB];
    int wv = threadIdx.x >> 6, lane = threadIdx.x & 63;
    int nbase = blockIdx.x*16;
    int node  = nbase + wv;

    // ---------- aggregation (one node per wave) ----------
    const float* fAf = (const float*)fAv;
    const bf16*  fAb = (const bf16*)fAv;
    const int i     = (CIN==64) ? lane : (lane & 31);
    const int kbase = (CIN==64) ? 0 : ((lane >> 5) * 8);
    unsigned cnt = curs[node]; if(cnt > 32u) cnt = 32u;
    const unsigned* crow = csr + (unsigned)node*32u;
    uint4 ca = ((const uint4*)crow)[0];
    uint4 cb = ((const uint4*)crow)[1];
    unsigned uu[8] = {ca.x, ca.y, ca.z, ca.w, cb.x, cb.y, cb.z, cb.w};

    constexpr int KPL = (CIN==64) ? 16 : 8;
    float acc[KPL];
    #pragma unroll
    for(int r=0;r<KPL;r++) acc[r] = 0.f;

    auto edge = [&](unsigned u){
        int sid = (int)(u & 16383u);
        int eid = (int)(u >> 14);
        float fe;
        if(CONCAT){
            fe = (lane < 32) ? fAf[sid*32 + lane] : fBv[sid*32 + (lane-32)];
        } else {
            fe = b2f(fAb[sid*CIN + i]);
        }
        const float4* gp = (const float4*)&g[(size_t)eid*16 + kbase];
        if(CIN==64){
            float4 g0=gp[0], g1=gp[1], g2=gp[2], g3=gp[3];
            acc[0]  += g0.x*fe; acc[1]  += g0.y*fe; acc[2]  += g0.z*fe; acc[3]  += g0.w*fe;
            acc[4]  += g1.x*fe; acc[5]  += g1.y*fe; acc[6]  += g1.z*fe; acc[7]  += g1.w*fe;
            acc[8]  += g2.x*fe; acc[9]  += g2.y*fe; acc[10] += g2.z*fe; acc[11] += g2.w*fe;
            acc[12] += g3.x*fe; acc[13] += g3.y*fe; acc[14] += g3.z*fe; acc[15] += g3.w*fe;
        } else {
            float4 g0=gp[0], g1=gp[1];
            acc[0] += g0.x*fe; acc[1] += g0.y*fe; acc[2] += g0.z*fe; acc[3] += g0.w*fe;
            acc[4] += g1.x*fe; acc[5] += g1.y*fe; acc[6] += g1.z*fe; acc[7] += g1.w*fe;
        }
    };
    #pragma unroll
    for(int j=0;j<8;j++){
        if((unsigned)j < cnt) edge(uu[j]);
    }
    for(unsigned j=8; j<cnt; j++) edge(crow[j]);

    // ---------- LDS write (swizzled) ----------
    unsigned xo_ = (unsigned)((wv & 7) << 4);
    if(CIN==64){
        #pragma unroll
        for(int k=0;k<16;k++){
            unsigned byte = (unsigned)wv*ROWB + ((((unsigned)(k*64 + lane))*2u) ^ xo_);
            *(bf16*)(sT + byte) = f2b(acc[k]);
        }
    } else {
        #pragma unroll
        for(int r=0;r<8;r++){
            unsigned byte = (unsigned)wv*ROWB + ((((unsigned)((kbase+r)*32 + i))*2u) ^ xo_);
            *(bf16*)(sT + byte) = f2b(acc[r]);
        }
    }
    __syncthreads();

    // ---------- GEMM from LDS (waves 0..NCT-1, full K) ----------
    if(wv >= NCT) return;
    int r = lane & 15, h = lane >> 4;
    int c = wv;
    const short8* Bp8 = (const short8*)Bp;
    f32x4 acc4 = (f32x4){0.f,0.f,0.f,0.f};
    unsigned xr = (unsigned)((r & 7) << 4);
    #pragma unroll 8
    for(int ks=0; ks<KD/32; ks++){
        unsigned ab = (unsigned)r*ROWB + (((unsigned)(ks*64 + h*16)) ^ xr);
        short8 af  = *(const short8*)(sT + ab);
        short8 bfr = Bp8[(ks*NCT + c)*64 + lane];
        acc4 = __builtin_amdgcn_mfma_f32_16x16x32_bf16(af, bfr, acc4, 0, 0, 0);
    }

    // ---------- epilogue ----------
    const int Cout = NCT*16;
    int col = c*16 + r;
    float inv = rsqrtf(bnv[col] + 1e-5f);
    float al  = bns[col] * inv;
    float be  = al*(bias[col] - bnm[col]) + bno[col];
    #pragma unroll
    for(int j=0;j<4;j++){
        int rr = nbase + h*4 + j;
        float v = al*acc4[j] + be;
        if(MODE==0){
            out[(size_t)rr*Cout + col] = (OT)fmaxf(v, 0.f);
        } else {
            float wei = 1.f/(1.f + __expf(-v));
            float xv = x[rr*32 + col];
            float yv = y[rr*32 + col];
            out[(size_t)rr*32 + col] = (OT)(2.f*xv*wei + 2.f*yv*(1.f - wei));
        }
    }
}

// ================= launch =================
extern "C" void kernel_launch(void* const* d_in, const int* in_sizes, int n_in,
                              void* d_out, int out_size, void* d_ws, size_t ws_size,
                              hipStream_t stream){
    const float* x   = (const float*)d_in[0];
    const float* y   = (const float*)d_in[1];
    const int* send  = (const int*)d_in[2];
    const int* recv  = (const int*)d_in[3];
    const float* rel = (const float*)d_in[4];
    const float* a   = (const float*)d_in[5];
    const float *W[4], *P[4], *bb[4], *bs[4], *bo[4], *bm[4], *bv[4];
    for(int i=0;i<4;i++){
        int base = 6 + i*7;
        W[i]  = (const float*)d_in[base+0];
        P[i]  = (const float*)d_in[base+1];
        bb[i] = (const float*)d_in[base+2];
        bs[i] = (const float*)d_in[base+3];
        bo[i] = (const float*)d_in[base+4];
        bm[i] = (const float*)d_in[base+5];
        bv[i] = (const float*)d_in[base+6];
    }
    char* w = (char*)d_ws;
    float*    g    = (float*)(w);                   // 16,777,216 B
    unsigned* curs = (unsigned*)(w + 16777216);     //     65,536 B
    unsigned* csr  = (unsigned*)(w + 16842752);     //  2,097,152 B
    bf16*     h1   = (bf16*)(w + 18939904);         //  2,097,152 B
    bf16*     xo   = (bf16*)(w + 21037056);         //  1,048,576 B
    bf16*     h3   = (bf16*)(w + 22085632);         //  2,097,152 B
    bf16*     Bp   = (bf16*)(w + 24182784);         //    327,680 B
    float*    outp = (float*)d_out;

    k_init     <<<400, 256, 0, stream>>>(curs, rel, a, P[0], P[1], P[2], P[3], g,
                                         W[0], W[1], W[2], W[3], Bp);
    k_countfill<<<NE/256, 256, 0, stream>>>(recv, send, curs, csr);

    // DIAGNOSTIC ROUND: run the 4 convs TWICE (idempotent re-execution).
    // delta vs R5's 98.3us = 4*C + 4*B (C = per-conv cost, B = per-boundary).
    for(int rep=0; rep<2; rep++){
        // conv1: [x|y] -> h1 (BN+relu)
        (k_conv<64,4,0,true,bf16>)  <<<NN/16, 1024, 0, stream>>>(x, y, g + (size_t)0*NE*16, csr, curs,
            Bp + (size_t)0*8,     bb[0], bs[0], bo[0], bm[0], bv[0], nullptr, nullptr, h1);
        // conv2: h1 -> wei1 -> xo (AFF)
        (k_conv<64,2,1,false,bf16>) <<<NN/16, 1024, 0, stream>>>(h1, nullptr, g + (size_t)1*NE*16, csr, curs,
            Bp + (size_t)8192*8,  bb[1], bs[1], bo[1], bm[1], bv[1], x, y, xo);
        // conv3: xo -> h3 (BN+relu)
        (k_conv<32,4,0,false,bf16>) <<<NN/16, 1024, 0, stream>>>(xo, nullptr, g + (size_t)2*NE*16, csr, curs,
            Bp + (size_t)12288*8, bb[2], bs[2], bo[2], bm[2], bv[2], nullptr, nullptr, h3);
        // conv4: h3 -> wei2 -> out (AFF, f32)
        (k_conv<64,2,1,false,float>)<<<NN/16, 1024, 0, stream>>>(h3, nullptr, g + (size_t)3*NE*16, csr, curs,
            Bp + (size_t)16384*8, bb[3], bs[3], bo[3], bm[3], bv[3], x, y, outp);
    }
}